// Round 11
// baseline (135.338 us; speedup 1.0000x reference)
//
#include <hip/hip_runtime.h>
#include <hip/hip_bf16.h>

#define NROWS 131072
#define KEXP 16
#define MPC 128
#define DIMD 64

typedef float f32x4 __attribute__((ext_vector_type(4)));
typedef short s16x8 __attribute__((ext_vector_type(8)));

#define L2E 1.4426950408889634f
#define LN2 0.6931471805599453f
#define BIAS_OFF 262144   // byte offset of bias_scaled table (A region = 16 x 16 KB)

static __device__ inline unsigned int b2u(__hip_bfloat162 h) {
    union { __hip_bfloat162 h; unsigned int u; } c;
    c.h = h;
    return c.u;
}

static __device__ inline int4 cvt8s(float4 f0, float4 f1, float sc) {
    __hip_bfloat162 p0 = __float22bfloat162_rn(make_float2(f0.x * sc, f0.y * sc));
    __hip_bfloat162 p1 = __float22bfloat162_rn(make_float2(f0.z * sc, f0.w * sc));
    __hip_bfloat162 p2 = __float22bfloat162_rn(make_float2(f1.x * sc, f1.y * sc));
    __hip_bfloat162 p3 = __float22bfloat162_rn(make_float2(f1.z * sc, f1.w * sc));
    int4 pk;
    pk.x = (int)b2u(p0); pk.y = (int)b2u(p1); pk.z = (int)b2u(p2); pk.w = (int)b2u(p3);
    return pk;
}

// async 16B/lane global->LDS DMA (wave-uniform LDS base + lane*16)
static __device__ inline void async_copy16(const void* g, void* l) {
    __builtin_amdgcn_global_load_lds(
        (const __attribute__((address_space(1))) unsigned int*)g,
        (__attribute__((address_space(3))) unsigned int*)l, 16, 0, 0);
}

// abff layout:
//  A region (256 KB): per expert k, 16 chunks c2 = mt*2+kc (mt 0..7, kc 0..1) of
//    1 KB; lane ul: 8 bf16 = a[k][mt*16 + (ul&15)][kc*32 + (ul>>4)*8 + j] * L2E
//    (byte-identical to the R7-verified 16x16x32 A pack).
//  bias_scaled (8 KB @ BIAS_OFF): bs[k*128+m] = b[k][m] * L2E (f32).
// Also zeroes out[].
__global__ void prep_kernel(const float* __restrict__ a, const float* __restrict__ b,
                            short* __restrict__ abff, float* __restrict__ out) {
    const int u = blockIdx.x * 256 + threadIdx.x;   // 80*256 = 20480
    if (u < 16384) {
        const int k  = u >> 10;
        const int c2 = (u >> 6) & 15;
        const int ul = u & 63;
        const int mt = c2 >> 1;
        const int kc = c2 & 1;
        const float* p = a + (size_t)(k * MPC + mt * 16 + (ul & 15)) * DIMD
                           + kc * 32 + (ul >> 4) * 8;
        int4 pk = cvt8s(*(const float4*)(p), *(const float4*)(p + 4), L2E);
        *(int4*)(abff + (size_t)u * 8) = pk;
    } else if (u < 16384 + 2048) {
        const int v = u - 16384;
        ((float*)((char*)abff + BIAS_OFF))[v] = b[v] * L2E;
    }
    for (int i = u; i < NROWS; i += 80 * 256) out[i] = 0.f;
}

// Round-11: structure DESIGNED for <=64 total regs (true 8 waves/SIMD), not
// squeezed into it. Evidence: 4 clean structures all 55-60us at 4 waves/SIMD
// with ~50% SIMD-issue stall; barriers (R9), ILP (R6), trans offload (R10),
// direct-global (R8) all eliminated. Occupancy is the last untested lever; the
// three prior spills (R3/R5/R7) were ~70-reg structures forced under 64.
// This one: 16 rows/wave (Bf = 8 regs), mfma_16x16x32 (acc = 4 regs), bias via
// prescaled f32 table (1 L1-resident float4/mt-step: no bias chunk, no bias
// MFMA), branch-free DMA (2 chunks/wave/stage), runtime k-loop. Est ~50 regs.
// LDS 2x8 KB -> 8 blocks/CU x 4 waves = 32 waves/CU. Family split x2, atomics
// into prep-zeroed out (R4-verified). Fragment math = R7-verified mapping.
// Spill canary: WRITE_SIZE must stay ~1 MB — if it balloons, 8-wave is dead
// for good; if clean and flat, the 55us floor is declared next round.
__global__ __launch_bounds__(256, 8)
void fused_kernel(const float* __restrict__ x, const float* __restrict__ s,
                  const short* __restrict__ abff, float* __restrict__ out) {
    __shared__ int4 abuf[2][512];   // 2 x 8 KB: chunk (mtl,kc) at mtl*2048 + kc*1024

    const int tid = threadIdx.x;
    const int w   = tid >> 6;
    const int l   = tid & 63;
    const int lq  = l >> 4;         // row-group 0..3

    const int family = blockIdx.x & 1;
    const int r0     = (blockIdx.x >> 1) * 64 + w * 16;   // wave owns 16 rows

    const int kf0 = family * 8;
    const char* ab = (const char*)abff;
    const float* bs = (const float*)(ab + BIAS_OFF);

    // initial DMA: expert kf0 half 0 -> abuf[0]; wave w copies chunks w, w+4
    {
        const char* src = ab + (size_t)kf0 * 16384 + l * 16;
        async_copy16(src + w * 1024,       (char*)&abuf[0][0] + w * 1024);
        async_copy16(src + (w + 4) * 1024, (char*)&abuf[0][0] + (w + 4) * 1024);
    }

    // persistent x B-fragments (load overlaps the DMA):
    // Bf[kc] = x[r0 + (l&15)][kc*32 + (l>>4)*8 ..+7]
    union { int4 i; s16x8 v; } Bf[2];
#pragma unroll
    for (int kc = 0; kc < 2; ++kc) {
        const float* gp = x + (size_t)(r0 + (l & 15)) * DIMD + kc * 32 + lq * 8;
        float4 f0 = *(const float4*)(gp);
        float4 f1 = *(const float4*)(gp + 4);
        Bf[kc].i = cvt8s(f0, f1, 1.0f);
    }

    __syncthreads();   // drains DMA (vmcnt0 before s_barrier)

    float racc = 0.f;

    for (int k = 0; k < 8; ++k) {   // runtime loop: small code, small regs
        const int kf = kf0 + k;
        const float sk2 = s[kf] * LN2;
        float e0 = 0.f, e1 = 0.f, e2 = 0.f, e3 = 0.f;

        // ---- half 0: prefetch half 1 -> abuf[1]; compute abuf[0] (mt 0..3)
        {
            const char* src = ab + (size_t)kf * 16384 + 8192 + l * 16;
            async_copy16(src + w * 1024,       (char*)&abuf[1][0] + w * 1024);
            async_copy16(src + (w + 4) * 1024, (char*)&abuf[1][0] + (w + 4) * 1024);
        }
#pragma unroll
        for (int mtl = 0; mtl < 4; ++mtl) {
            const char* base = (const char*)&abuf[0][0] + mtl * 2048 + l * 16;
            f32x4 acc = *(const f32x4*)(bs + kf * MPC + mtl * 16 + lq * 4);
            s16x8 Af0 = *(const s16x8*)(base);
            acc = __builtin_amdgcn_mfma_f32_16x16x32_bf16(Af0, Bf[0].v, acc, 0, 0, 0);
            s16x8 Af1 = *(const s16x8*)(base + 1024);
            acc = __builtin_amdgcn_mfma_f32_16x16x32_bf16(Af1, Bf[1].v, acc, 0, 0, 0);
            e0 += __builtin_amdgcn_exp2f(acc[0]);
            e1 += __builtin_amdgcn_exp2f(acc[1]);
            e2 += __builtin_amdgcn_exp2f(acc[2]);
            e3 += __builtin_amdgcn_exp2f(acc[3]);
        }
        __syncthreads();   // abuf[0] free; abuf[1] drained

        // ---- half 1: prefetch next expert half 0 -> abuf[0]; compute abuf[1] (mt 4..7)
        if (k < 7) {
            const char* src = ab + (size_t)(kf + 1) * 16384 + l * 16;
            async_copy16(src + w * 1024,       (char*)&abuf[0][0] + w * 1024);
            async_copy16(src + (w + 4) * 1024, (char*)&abuf[0][0] + (w + 4) * 1024);
        }
#pragma unroll
        for (int mtl = 0; mtl < 4; ++mtl) {
            const char* base = (const char*)&abuf[1][0] + mtl * 2048 + l * 16;
            f32x4 acc = *(const f32x4*)(bs + kf * MPC + 64 + mtl * 16 + lq * 4);
            s16x8 Af0 = *(const s16x8*)(base);
            acc = __builtin_amdgcn_mfma_f32_16x16x32_bf16(Af0, Bf[0].v, acc, 0, 0, 0);
            s16x8 Af1 = *(const s16x8*)(base + 1024);
            acc = __builtin_amdgcn_mfma_f32_16x16x32_bf16(Af1, Bf[1].v, acc, 0, 0, 0);
            e0 += __builtin_amdgcn_exp2f(acc[0]);
            e1 += __builtin_amdgcn_exp2f(acc[1]);
            e2 += __builtin_amdgcn_exp2f(acc[2]);
            e3 += __builtin_amdgcn_exp2f(acc[3]);
        }

        // m-sum: lane holds 4 rows; row-groups at lanes l, l^16, l^32, l^48
        float tot = (e0 + e1) + (e2 + e3);
        tot += __shfl_xor(tot, 16);
        tot += __shfl_xor(tot, 32);
        racc = fmaf(sk2, __log2f(tot), racc);

        __syncthreads();   // abuf[1] free; abuf[0] (next expert) drained
    }

    // col n = r0 + (l&15); lanes l<16 write (one atomic per row per family)
    if (l < 16)
        atomicAdd(&out[r0 + l], racc);
}

extern "C" void kernel_launch(void* const* d_in, const int* in_sizes, int n_in,
                              void* d_out, int out_size, void* d_ws, size_t ws_size,
                              hipStream_t stream) {
    const float* x = (const float*)d_in[0];
    const float* s = (const float*)d_in[1];
    const float* a = (const float*)d_in[2];
    const float* b = (const float*)d_in[3];
    float* out = (float*)d_out;

    short* abff = (short*)d_ws;   // A 256 KB + bias_scaled 8 KB

    prep_kernel<<<80, 256, 0, stream>>>(a, b, abff, out);
    fused_kernel<<<NROWS / 32, 256, 0, stream>>>(x, s, abff, out);
}

// Round 12
// 133.243 us; speedup vs baseline: 1.0157x; 1.0157x over previous
//
#include <hip/hip_runtime.h>
#include <hip/hip_bf16.h>

#define NROWS 131072
#define KEXP 16
#define MPC 128
#define DIMD 64

typedef float f32x4 __attribute__((ext_vector_type(4)));
typedef short s16x8 __attribute__((ext_vector_type(8)));

#define L2E 1.4426950408889634f
#define LN2 0.6931471805599453f
#define BIAS_OFF 262144   // byte offset of bias region (A region = 16 x 16 KB)

static __device__ inline unsigned int b2u(__hip_bfloat162 h) {
    union { __hip_bfloat162 h; unsigned int u; } c;
    c.h = h;
    return c.u;
}

static __device__ inline int4 cvt8s(float4 f0, float4 f1, float sc) {
    __hip_bfloat162 p0 = __float22bfloat162_rn(make_float2(f0.x * sc, f0.y * sc));
    __hip_bfloat162 p1 = __float22bfloat162_rn(make_float2(f0.z * sc, f0.w * sc));
    __hip_bfloat162 p2 = __float22bfloat162_rn(make_float2(f1.x * sc, f1.y * sc));
    __hip_bfloat162 p3 = __float22bfloat162_rn(make_float2(f1.z * sc, f1.w * sc));
    int4 pk;
    pk.x = (int)b2u(p0); pk.y = (int)b2u(p1); pk.z = (int)b2u(p2); pk.w = (int)b2u(p3);
    return pk;
}

// async 16B/lane global->LDS DMA (wave-uniform LDS base + lane*16)
static __device__ inline void async_copy16(const void* g, void* l) {
    __builtin_amdgcn_global_load_lds(
        (const __attribute__((address_space(1))) unsigned int*)g,
        (__attribute__((address_space(3))) unsigned int*)l, 16, 0, 0);
}

// abff layout:
//  A region (256 KB): per expert k, 16 chunks c2 = mt*2+kc (mt 0..7, kc 0..1) of
//    1 KB; lane ul: 8 bf16 = a[k][mt*16 + (ul&15)][kc*32 + (ul>>4)*8 + j] * L2E
//    (byte-identical to the R7/R11-verified 16x16x32 A pack).
//  bias region (32 KB @ BIAS_OFF): per (k, half h) one 1 KB slot (R7-verified
//    mapping): slot floats [0..63] = b[k][h*64 + i] * L2E, rest padding.
// Also zeroes out[].
__global__ void prep_kernel(const float* __restrict__ a, const float* __restrict__ b,
                            short* __restrict__ abff, float* __restrict__ out) {
    const int u = blockIdx.x * 256 + threadIdx.x;   // 80*256 = 20480
    if (u < 16384) {
        const int k  = u >> 10;
        const int c2 = (u >> 6) & 15;
        const int ul = u & 63;
        const int mt = c2 >> 1;
        const int kc = c2 & 1;
        const float* p = a + (size_t)(k * MPC + mt * 16 + (ul & 15)) * DIMD
                           + kc * 32 + (ul >> 4) * 8;
        int4 pk = cvt8s(*(const float4*)(p), *(const float4*)(p + 4), L2E);
        *(int4*)(abff + (size_t)u * 8) = pk;
    } else if (u < 16384 + 2048) {
        const int v = u - 16384;
        const int k = v >> 7;
        const int m = v & 127;
        float* bf = (float*)((char*)abff + BIAS_OFF);
        bf[(size_t)(k * 2 + (m >> 6)) * 256 + (m & 63)] = b[k * MPC + m] * L2E;
    }
    for (int i = u; i < NROWS; i += 80 * 256) out[i] = 0.f;
}

// Round-12: the ONE clean experiment never run — R4's AMORTIZED dataflow at a
// TRUE 8 waves/SIMD. R11's 8-wave null was confounded: it halved rows/wave
// (2x instrs per FLOP; issue count tracked dur almost exactly) AND put a
// global bias load in the acc dependency chain. This kernel: 16x16x32 MFMA,
// TWO n-tiles per wave (32 rows — A-frags and bias shared by both accs, same
// per-row staging cost as R4), bias staged in LDS (broadcast ds_read_b128
// initializes both accs; no bias MFMA, no global load in chain). Honest live
// set ~50 regs (Bf 16 + acc 8 + esum/racc 4 + transients + addressing) —
// genuine slack under the 64-reg/8-wave boundary, unlike the ~70-reg spills
// (R3/R5/R7). LDS 2 x 9 KB = 18 KB -> 8 blocks/CU -> 32 waves/CU.
// Spill canary: WRITE_SIZE ~1 MB. If clean-8-wave AND flat: floor is the
// dependency structure itself — declare empirical roofline.
__global__ __launch_bounds__(256, 8)
void fused_kernel(const float* __restrict__ x, const float* __restrict__ s,
                  const short* __restrict__ abff, float* __restrict__ out) {
    // per buffer: A chunks 0..7 at ch*1024 (8 KB), bias slot at 8192 (1 KB)
    __shared__ int4 abuf[2][576];   // 2 x 9 KB

    const int tid = threadIdx.x;
    const int w   = tid >> 6;
    const int l   = tid & 63;
    const int lq  = l >> 4;         // 16-lane group 0..3

    const int family = blockIdx.x & 1;
    const int r0     = (blockIdx.x >> 1) * 128 + w * 32;   // wave owns 32 rows

    const int kf0 = family * 8;
    const char* ab = (const char*)abff;

    // initial DMA: expert kf0 half 0 -> abuf[0] (8 A chunks + bias slot = 9)
    {
        const char* srcA = ab + (size_t)kf0 * 16384 + l * 16;
        const char* srcB = ab + BIAS_OFF + (size_t)kf0 * 2048 + l * 16;
#pragma unroll
        for (int i = 0; i < 3; ++i) {
            const int ch = w + 4 * i;
            if (ch < 8)
                async_copy16(srcA + ch * 1024, (char*)&abuf[0][0] + ch * 1024);
            else if (ch == 8)
                async_copy16(srcB, (char*)&abuf[0][0] + 8192);
        }
    }

    // persistent x B-fragments (overlap the DMA):
    // Bf[nt][kc] = x[r0 + nt*16 + (l&15)][kc*32 + lq*8 ..+7]
    union { int4 i; s16x8 v; } Bf[2][2];
#pragma unroll
    for (int nt = 0; nt < 2; ++nt)
#pragma unroll
        for (int kc = 0; kc < 2; ++kc) {
            const float* gp = x + (size_t)(r0 + nt * 16 + (l & 15)) * DIMD
                                + kc * 32 + lq * 8;
            float4 f0 = *(const float4*)(gp);
            float4 f1 = *(const float4*)(gp + 4);
            Bf[nt][kc].i = cvt8s(f0, f1, 1.0f);
        }

    __syncthreads();   // drains DMA (vmcnt0 before s_barrier)

    float racc0 = 0.f, racc1 = 0.f;

    for (int k = 0; k < 8; ++k) {   // runtime loop: small code, small regs
        const int kf = kf0 + k;
        const float sk2 = s[kf] * LN2;
        float e0 = 0.f, e1 = 0.f;

        // ---- half 0: prefetch (kf, half1) -> abuf[1]; compute abuf[0] (mt 0..3)
        {
            const char* srcA = ab + (size_t)kf * 16384 + 8192 + l * 16;
            const char* srcB = ab + BIAS_OFF + (size_t)kf * 2048 + 1024 + l * 16;
#pragma unroll
            for (int i = 0; i < 3; ++i) {
                const int ch = w + 4 * i;
                if (ch < 8)
                    async_copy16(srcA + ch * 1024, (char*)&abuf[1][0] + ch * 1024);
                else if (ch == 8)
                    async_copy16(srcB, (char*)&abuf[1][0] + 8192);
            }
        }
#pragma unroll
        for (int mtl = 0; mtl < 4; ++mtl) {
            const char* Ab = (const char*)&abuf[0][0];
            // bias broadcast: m = half*64 + mtl*16 + lq*4 + r  (same for both ntiles)
            f32x4 bv = *(const f32x4*)(Ab + 8192 + mtl * 64 + lq * 16);
            f32x4 acc0 = bv, acc1 = bv;
            s16x8 Af0 = *(const s16x8*)(Ab + (mtl * 2 + 0) * 1024 + l * 16);
            acc0 = __builtin_amdgcn_mfma_f32_16x16x32_bf16(Af0, Bf[0][0].v, acc0, 0, 0, 0);
            acc1 = __builtin_amdgcn_mfma_f32_16x16x32_bf16(Af0, Bf[1][0].v, acc1, 0, 0, 0);
            s16x8 Af1 = *(const s16x8*)(Ab + (mtl * 2 + 1) * 1024 + l * 16);
            acc0 = __builtin_amdgcn_mfma_f32_16x16x32_bf16(Af1, Bf[0][1].v, acc0, 0, 0, 0);
            acc1 = __builtin_amdgcn_mfma_f32_16x16x32_bf16(Af1, Bf[1][1].v, acc1, 0, 0, 0);
            e0 += __builtin_amdgcn_exp2f(acc0[0]);
            e0 += __builtin_amdgcn_exp2f(acc0[1]);
            e0 += __builtin_amdgcn_exp2f(acc0[2]);
            e0 += __builtin_amdgcn_exp2f(acc0[3]);
            e1 += __builtin_amdgcn_exp2f(acc1[0]);
            e1 += __builtin_amdgcn_exp2f(acc1[1]);
            e1 += __builtin_amdgcn_exp2f(acc1[2]);
            e1 += __builtin_amdgcn_exp2f(acc1[3]);
        }
        __syncthreads();   // abuf[0] free; abuf[1] drained

        // ---- half 1: prefetch (kf+1, half0) -> abuf[0]; compute abuf[1] (mt 4..7)
        if (k < 7) {
            const char* srcA = ab + (size_t)(kf + 1) * 16384 + l * 16;
            const char* srcB = ab + BIAS_OFF + (size_t)(kf + 1) * 2048 + l * 16;
#pragma unroll
            for (int i = 0; i < 3; ++i) {
                const int ch = w + 4 * i;
                if (ch < 8)
                    async_copy16(srcA + ch * 1024, (char*)&abuf[0][0] + ch * 1024);
                else if (ch == 8)
                    async_copy16(srcB, (char*)&abuf[0][0] + 8192);
            }
        }
#pragma unroll
        for (int mtl = 0; mtl < 4; ++mtl) {
            const char* Ab = (const char*)&abuf[1][0];
            f32x4 bv = *(const f32x4*)(Ab + 8192 + mtl * 64 + lq * 16);
            f32x4 acc0 = bv, acc1 = bv;
            s16x8 Af0 = *(const s16x8*)(Ab + (mtl * 2 + 0) * 1024 + l * 16);
            acc0 = __builtin_amdgcn_mfma_f32_16x16x32_bf16(Af0, Bf[0][0].v, acc0, 0, 0, 0);
            acc1 = __builtin_amdgcn_mfma_f32_16x16x32_bf16(Af0, Bf[1][0].v, acc1, 0, 0, 0);
            s16x8 Af1 = *(const s16x8*)(Ab + (mtl * 2 + 1) * 1024 + l * 16);
            acc0 = __builtin_amdgcn_mfma_f32_16x16x32_bf16(Af1, Bf[0][1].v, acc0, 0, 0, 0);
            acc1 = __builtin_amdgcn_mfma_f32_16x16x32_bf16(Af1, Bf[1][1].v, acc1, 0, 0, 0);
            e0 += __builtin_amdgcn_exp2f(acc0[0]);
            e0 += __builtin_amdgcn_exp2f(acc0[1]);
            e0 += __builtin_amdgcn_exp2f(acc0[2]);
            e0 += __builtin_amdgcn_exp2f(acc0[3]);
            e1 += __builtin_amdgcn_exp2f(acc1[0]);
            e1 += __builtin_amdgcn_exp2f(acc1[1]);
            e1 += __builtin_amdgcn_exp2f(acc1[2]);
            e1 += __builtin_amdgcn_exp2f(acc1[3]);
        }

        // m-sum: lane covers m-groups via lq; reduce lanes l, l^16, l^32, l^48
        float tot0 = e0, tot1 = e1;
        tot0 += __shfl_xor(tot0, 16);
        tot0 += __shfl_xor(tot0, 32);
        tot1 += __shfl_xor(tot1, 16);
        tot1 += __shfl_xor(tot1, 32);
        racc0 = fmaf(sk2, __log2f(tot0), racc0);
        racc1 = fmaf(sk2, __log2f(tot1), racc1);

        __syncthreads();   // abuf[1] free; abuf[0] (next expert) drained
    }

    // n = r0 + (l&15) for ntile0 (racc0), r0 + 16 + (l&15) for ntile1 (racc1)
    if (l < 16) {
        atomicAdd(&out[r0 + l], racc0);
        atomicAdd(&out[r0 + 16 + l], racc1);
    }
}

extern "C" void kernel_launch(void* const* d_in, const int* in_sizes, int n_in,
                              void* d_out, int out_size, void* d_ws, size_t ws_size,
                              hipStream_t stream) {
    const float* x = (const float*)d_in[0];
    const float* s = (const float*)d_in[1];
    const float* a = (const float*)d_in[2];
    const float* b = (const float*)d_in[3];
    float* out = (float*)d_out;

    short* abff = (short*)d_ws;   // A 256 KB + bias 32 KB

    prep_kernel<<<80, 256, 0, stream>>>(a, b, abff, out);
    fused_kernel<<<NROWS / 64, 256, 0, stream>>>(x, s, abff, out);
}

// Round 13
// 122.883 us; speedup vs baseline: 1.1014x; 1.0843x over previous
//
#include <hip/hip_runtime.h>
#include <hip/hip_bf16.h>

#define NROWS 131072
#define KEXP 16
#define MPC 128
#define DIMD 64

typedef float f32x16 __attribute__((ext_vector_type(16)));
typedef short s16x8  __attribute__((ext_vector_type(8)));

#define L2E 1.4426950408889634f
#define LN2 0.6931471805599453f

static __device__ inline unsigned int b2u(__hip_bfloat162 h) {
    union { __hip_bfloat162 h; unsigned int u; } c;
    c.h = h;
    return c.u;
}

static __device__ inline int4 cvt8s(float4 f0, float4 f1, float sc) {
    __hip_bfloat162 p0 = __float22bfloat162_rn(make_float2(f0.x * sc, f0.y * sc));
    __hip_bfloat162 p1 = __float22bfloat162_rn(make_float2(f0.z * sc, f0.w * sc));
    __hip_bfloat162 p2 = __float22bfloat162_rn(make_float2(f1.x * sc, f1.y * sc));
    __hip_bfloat162 p3 = __float22bfloat162_rn(make_float2(f1.z * sc, f1.w * sc));
    int4 pk;
    pk.x = (int)b2u(p0); pk.y = (int)b2u(p1); pk.z = (int)b2u(p2); pk.w = (int)b2u(p3);
    return pk;
}

// async 16B/lane global->LDS DMA (wave-uniform LDS base + lane*16)
static __device__ inline void async_copy16(const void* g, void* l) {
    __builtin_amdgcn_global_load_lds(
        (const __attribute__((address_space(1))) unsigned int*)g,
        (__attribute__((address_space(3))) unsigned int*)l, 16, 0, 0);
}

// abff: per expert 20 chunks [mt(4)][c(5)] of 64 int4 (1 KB each) = 20 KB.
//   c<4 : A-frag, value j = a[k][mt*32 + (ul&31)][c*16 + (ul>>5)*8 + j] * L2E
//   c==4: bias chunk — A[m][k'=0] = b[k][mt*32+m] * L2E (ul<32, element 0), else 0
// (R0/R4-verified layout; out-zero pass dropped — fused now plain-stores.)
__global__ void prep_kernel(const float* __restrict__ a, const float* __restrict__ b,
                            short* __restrict__ abff) {
    const int u   = blockIdx.x * 256 + threadIdx.x;   // 0..20479
    const int k   = u / 1280;
    const int rem = u - k * 1280;
    const int mt  = rem / 320;
    const int rc  = rem - mt * 320;
    const int c   = rc >> 6;
    const int ul  = rc & 63;
    int4 pk;
    if (c < 4) {
        const float* p = a + (size_t)(k * MPC + mt * 32 + (ul & 31)) * DIMD
                           + c * 16 + (ul >> 5) * 8;
        pk = cvt8s(*(const float4*)(p), *(const float4*)(p + 4), L2E);
    } else {
        pk.x = 0; pk.y = 0; pk.z = 0; pk.w = 0;
        if (ul < 32) {
            union { __hip_bfloat16 h; unsigned short us; } cv;
            cv.h = __float2bfloat16(b[k * MPC + mt * 32 + ul] * L2E);
            pk.x = (int)cv.us;   // element 0 = bias, elements 1..7 = 0
        }
    }
    *(int4*)(abff + (size_t)u * 8) = pk;
}

// Round-13: CONSOLIDATION. The 12-round ledger brackets the fused floor at
// 55-60us: six clean structures (4 and 8 waves/SIMD), barriers/ILP/trans-
// offload/direct-global all individually falsified; no pipe >50%; the 64-reg
// 8-wave regime spills in every amortized variant (R3/R5/R7/R12). This kernel
// restores the most-verified best structure (R4: 55.0us, 52 VGPR, no spills)
// with two subtractive edits targeting the TOTAL: no family split (each block
// walks all 16 experts -> each row plain-stored exactly once, atomics gone)
// and no out-zeroing in prep. Inner loop byte-identical to R4.
__global__ __launch_bounds__(256, 4)
void fused_kernel(const float* __restrict__ x, const float* __restrict__ s,
                  const short* __restrict__ abff, float* __restrict__ out) {
    __shared__ int4 abuf[2][640];   // 2 x 10 KB

    const int tid  = threadIdx.x;
    const int w    = tid >> 6;
    const int l    = tid & 63;
    const int ln   = l & 31;
    const int half = l >> 5;

    const int r0w = blockIdx.x * 128 + w * 32;

    // persistent x B-fragment: Bf[c] = x[r0w + ln][c*16 + half*8 ..+7]
    union { int4 i; s16x8 v; } Bf[4];
#pragma unroll
    for (int c = 0; c < 4; ++c) {
        const float* gp = x + (size_t)(r0w + ln) * DIMD + c * 16 + half * 8;
        float4 f0 = *(const float4*)(gp);
        float4 f1 = *(const float4*)(gp + 4);
        Bf[c].i = cvt8s(f0, f1, 1.0f);
    }

    // constant bias-B: B[n][k'=0] = 1.0 (k'=0 lives on half==0 lanes, element 0)
    union { int4 i; s16x8 v; } Bones;
    Bones.i.x = (half == 0) ? 0x3F80 : 0;   // bf16(1.0) in element 0
    Bones.i.y = 0; Bones.i.z = 0; Bones.i.w = 0;

    // DMA initial stage (expert 0, mtiles 0-1) into abuf[0]:
    // 10 chunks, wave w takes ch = w + 4*i
    {
        const short* src = abff;
#pragma unroll
        for (int i = 0; i < 3; ++i) {
            const int ch = w + 4 * i;
            if (ch < 10)
                async_copy16(src + ch * 512 + l * 8, (char*)&abuf[0][0] + ch * 1024);
        }
    }
    __syncthreads();   // barrier drains DMA (vmcnt0 before s_barrier)

    float racc = 0.f;

    for (int k = 0; k < KEXP; ++k) {   // runtime loop: keep code + registers small
        const float sk2 = s[k] * LN2;
        float esum = 0.f;

        // ---------- half-stage 0: compute abuf[0], prefetch half 1 -> abuf[1]
        {
            const short* src = abff + (size_t)k * 10240 + 5120;
#pragma unroll
            for (int i = 0; i < 3; ++i) {
                const int ch = w + 4 * i;
                if (ch < 10)
                    async_copy16(src + ch * 512 + l * 8, (char*)&abuf[1][0] + ch * 1024);
            }
        }
#pragma unroll
        for (int mtl = 0; mtl < 2; ++mtl) {
            const short* base = (const short*)&abuf[0][0] + mtl * 5 * 512 + l * 8;
            f32x16 acc = {};
#pragma unroll
            for (int c = 0; c < 4; ++c) {
                s16x8 Af = *(const s16x8*)(base + c * 512);   // JIT load, short live range
                acc = __builtin_amdgcn_mfma_f32_32x32x16_bf16(Af, Bf[c].v, acc, 0, 0, 0);
            }
            {
                s16x8 Af = *(const s16x8*)(base + 4 * 512);
                acc = __builtin_amdgcn_mfma_f32_32x32x16_bf16(Af, Bones.v, acc, 0, 0, 0);
            }
            float s0 = 0.f, s1 = 0.f, s2 = 0.f, s3 = 0.f;
#pragma unroll
            for (int r = 0; r < 4; ++r) {
                s0 += __builtin_amdgcn_exp2f(acc[4 * r + 0]);
                s1 += __builtin_amdgcn_exp2f(acc[4 * r + 1]);
                s2 += __builtin_amdgcn_exp2f(acc[4 * r + 2]);
                s3 += __builtin_amdgcn_exp2f(acc[4 * r + 3]);
            }
            esum += (s0 + s1) + (s2 + s3);
        }
        __syncthreads();   // abuf[0] free; abuf[1] drained

        // ---------- half-stage 1: compute abuf[1], prefetch next expert -> abuf[0]
        if (k < KEXP - 1) {
            const short* src = abff + (size_t)(k + 1) * 10240;
#pragma unroll
            for (int i = 0; i < 3; ++i) {
                const int ch = w + 4 * i;
                if (ch < 10)
                    async_copy16(src + ch * 512 + l * 8, (char*)&abuf[0][0] + ch * 1024);
            }
        }
#pragma unroll
        for (int mtl = 0; mtl < 2; ++mtl) {
            const short* base = (const short*)&abuf[1][0] + mtl * 5 * 512 + l * 8;
            f32x16 acc = {};
#pragma unroll
            for (int c = 0; c < 4; ++c) {
                s16x8 Af = *(const s16x8*)(base + c * 512);
                acc = __builtin_amdgcn_mfma_f32_32x32x16_bf16(Af, Bf[c].v, acc, 0, 0, 0);
            }
            {
                s16x8 Af = *(const s16x8*)(base + 4 * 512);
                acc = __builtin_amdgcn_mfma_f32_32x32x16_bf16(Af, Bones.v, acc, 0, 0, 0);
            }
            float s0 = 0.f, s1 = 0.f, s2 = 0.f, s3 = 0.f;
#pragma unroll
            for (int r = 0; r < 4; ++r) {
                s0 += __builtin_amdgcn_exp2f(acc[4 * r + 0]);
                s1 += __builtin_amdgcn_exp2f(acc[4 * r + 1]);
                s2 += __builtin_amdgcn_exp2f(acc[4 * r + 2]);
                s3 += __builtin_amdgcn_exp2f(acc[4 * r + 3]);
            }
            esum += (s0 + s1) + (s2 + s3);
        }

        // combine m-halves (lanes l and l^32), accumulate weighted lse
        float tot = esum + __shfl_xor(esum, 32);
        racc = fmaf(sk2, __log2f(tot), racc);

        __syncthreads();   // abuf[1] free; abuf[0] (next expert) drained
    }

    // all 16 experts done in this block: each row written exactly once
    if (half == 0)
        out[r0w + ln] = racc;
}

extern "C" void kernel_launch(void* const* d_in, const int* in_sizes, int n_in,
                              void* d_out, int out_size, void* d_ws, size_t ws_size,
                              hipStream_t stream) {
    const float* x = (const float*)d_in[0];
    const float* s = (const float*)d_in[1];
    const float* a = (const float*)d_in[2];
    const float* b = (const float*)d_in[3];
    float* out = (float*)d_out;

    short* abff = (short*)d_ws;   // 16 experts x 20 KB = 320 KB

    prep_kernel<<<80, 256, 0, stream>>>(a, b, abff);
    fused_kernel<<<NROWS / 128, 256, 0, stream>>>(x, s, abff, out);
}